// Round 12
// baseline (763.433 us; speedup 1.0000x reference)
//
#include <hip/hip_runtime.h>
#include <cstdint>
#include <cstddef>

typedef unsigned short u16;
typedef unsigned char u8;
typedef __bf16 bf16x8 __attribute__((ext_vector_type(8)));
typedef float f32x4 __attribute__((ext_vector_type(4)));
typedef float f32x2 __attribute__((ext_vector_type(2)));
typedef u16 u16x4 __attribute__((ext_vector_type(4)));
typedef u16 u16x8 __attribute__((ext_vector_type(8)));

#define B_ 16384
#define D_ 64
#define MAXC_ 8
#define NCON_ 2000
#define NCONP_ 2048
#define TDIM_ 1024
#define HID_ 256
#define REP 8

#define VMW(n) asm volatile("s_waitcnt vmcnt(" #n ")" ::: "memory")
#define BAR() __builtin_amdgcn_s_barrier()
#define CLOBBER() asm volatile("" ::: "memory")

__device__ inline u16 f2b(float f){
  unsigned u = __float_as_uint(f);
  u += 0x7fffu + ((u >> 16) & 1u);
  return (u16)(u >> 16);
}
__device__ inline float b2f(u16 u){ return __uint_as_float(((unsigned)u) << 16); }

__device__ inline unsigned pk2fp8(float a, float b){
  return (unsigned)__builtin_amdgcn_cvt_pk_fp8_f32(a, b, 0, false);
}
template<bool HI>
__device__ inline f32x2 unpk_fp8(unsigned v){
  return __builtin_amdgcn_cvt_pk_f32_fp8(v, HI);
}

__device__ inline void gload16(const void* g, void* l){
  __builtin_amdgcn_global_load_lds((const __attribute__((address_space(1))) unsigned*)g,
                                   (__attribute__((address_space(3))) unsigned*)l, 16, 0, 0);
}

__device__ inline float wsum(float v){
  #pragma unroll
  for (int o = 32; o; o >>= 1) v += __shfl_xor(v, o);
  return v;
}
__device__ inline float sigf(float x){ return 1.f / (1.f + __expf(-x)); }

// =================== k_prep (x REP for attribution) =========================
// [0,4096): q gather -> qb(bf16)+qn ; [4096,4608): concepts -> cb,cb8,cn ;
// [4608,6017): weights
__global__ __launch_bounds__(256) void k_prep(
    const float* __restrict__ ex, const int* __restrict__ pid,
    const float* __restrict__ con,
    const float* __restrict__ W1, const float* __restrict__ W2,
    const float* __restrict__ Wx, const float* __restrict__ Wh,
    const float* __restrict__ bx, const float* __restrict__ bh,
    u16* __restrict__ qb, float* __restrict__ qn,
    u16* __restrict__ cb, u8* __restrict__ cb8, float* __restrict__ cn,
    u16* __restrict__ W1T, u16* __restrict__ W2T, u16* __restrict__ WxhT,
    float* __restrict__ bxh)
{
  const int bid = blockIdx.x, tid = threadIdx.x;
  const int lane = tid & 63;
  for (int rep = 0; rep < REP; ++rep){
  CLOBBER();
  if (bid < 4096){                                  // ---- q gather ----
    const int b = bid * 4 + (tid >> 6);
    const float* src = ex + (size_t)pid[b] * TDIM_;
    u16* dst = qb + (size_t)b * TDIM_;
    float ss = 0.f;
    #pragma unroll
    for (int c = 0; c < 4; ++c){
      float4 v = *(const float4*)(src + c * 256 + lane * 4);
      ss += v.x*v.x + v.y*v.y + v.z*v.z + v.w*v.w;
      u16x4 o = { f2b(v.x), f2b(v.y), f2b(v.z), f2b(v.w) };
      *(u16x4*)(dst + c * 256 + lane * 4) = o;
    }
    ss = wsum(ss);
    if (lane == 0) qn[b] = sqrtf(ss);
  } else if (bid < 4608){                           // ---- concepts ----
    const int r = (bid - 4096) * 4 + (tid >> 6);
    u16* dst = cb + (size_t)r * TDIM_;
    u8*  dst8 = cb8 + (size_t)r * TDIM_;
    if (r < NCON_){
      const float* src = con + (size_t)r * TDIM_;
      float ss = 0.f;
      #pragma unroll
      for (int c = 0; c < 4; ++c){
        float4 v = *(const float4*)(src + c * 256 + lane * 4);
        ss += v.x*v.x + v.y*v.y + v.z*v.z + v.w*v.w;
        u16x4 o = { f2b(v.x), f2b(v.y), f2b(v.z), f2b(v.w) };
        *(u16x4*)(dst + c * 256 + lane * 4) = o;
        unsigned lo = pk2fp8(v.x * 32.f, v.y * 32.f);
        unsigned hi = pk2fp8(v.z * 32.f, v.w * 32.f);
        *(unsigned*)(dst8 + c * 256 + lane * 4) = (lo & 0xffffu) | (hi << 16);
      }
      ss = wsum(ss);
      if (lane == 0) cn[r] = sqrtf(ss);
    } else {
      u16x4 z = { 0, 0, 0, 0 };
      #pragma unroll
      for (int c = 0; c < 4; ++c){
        *(u16x4*)(dst + c * 256 + lane * 4) = z;
        *(unsigned*)(dst8 + c * 256 + lane * 4) = 0u;
      }
    }
  } else {                                          // ---- weights ----
    int gid = (bid - 4608) * 256 + tid;
    if (gid < 262144){                       // W1T: n*1024 + k
      int n = gid >> 10, k = gid & 1023;
      W1T[gid] = f2b(W1[(size_t)k * 256 + n]);
    } else if (gid < 278528){                // W2T: n*256 + k
      int t = gid - 262144;
      int n = t >> 8, k = t & 255;
      W2T[t] = f2b(W2[(size_t)k * 64 + n]);
    } else if (gid < 360448){                // WxhT: c*320 + k, gate-interleaved
      int t = gid - 278528;
      int c = t / 320, k = t % 320;
      int g = (c >> 4) & 3;
      int d = (c >> 6) * 16 + (c & 15);
      float v = 0.f;
      if (k < 256){
        if (g == 0)      v = Wx[(size_t)k * 192 + d];
        else if (g == 1) v = Wx[(size_t)k * 192 + 64 + d];
        else if (g == 2) v = Wx[(size_t)k * 192 + 128 + d];
      } else {
        int kh = k - 256;
        if (g == 0)      v = Wh[(size_t)kh * 192 + d];
        else if (g == 1) v = Wh[(size_t)kh * 192 + 64 + d];
        else if (g == 3) v = Wh[(size_t)kh * 192 + 128 + d];
      }
      WxhT[t] = f2b(v);
    } else if (gid < 360704){                // bxh
      int c = gid - 360448;
      int g = (c >> 4) & 3;
      int d = (c >> 6) * 16 + (c & 15);
      float v;
      if (g == 0)      v = bx[d] + bh[d];
      else if (g == 1) v = bx[64 + d] + bh[64 + d];
      else if (g == 2) v = bx[128 + d];
      else             v = bh[128 + d];
      bxh[c] = v;
    }
  }
  }
}

// =================== k_mlp (x REP): red = relu(A@W1+b1)@W2+b2 ===============
// BM=32, 576 blocks x 512 thr (blocks [0,512): q rows; [512,576): c rows).
__global__ __launch_bounds__(512) void k_mlp(
    const u16* __restrict__ qb, const u16* __restrict__ cb,
    const u16* __restrict__ W1T, const float* __restrict__ b1,
    const u16* __restrict__ W2T, const float* __restrict__ b2,
    float* __restrict__ redq, float* __restrict__ redc)
{
  __shared__ u16 As[32 * 64];      // 4 KB
  __shared__ u16 Bs[256 * 64];     // 32 KB
  __shared__ u16 Hs[32 * 256];     // 16 KB
  const int tid = threadIdx.x;
  const int lane = tid & 63;
  const int w = tid >> 6;
  const int lr = lane & 15, lq = lane >> 4;
  const bool qside = blockIdx.x < 512;
  const u16* Abase = qside ? qb : cb;
  float* Obase = qside ? redq : redc;
  const int m0 = (qside ? (int)blockIdx.x : ((int)blockIdx.x - 512)) << 5;
  const int rf = w & 1, ch = w >> 1;
  const int arow = tid >> 3, asub = tid & 7;

  for (int rep = 0; rep < REP; ++rep){
  CLOBBER();
  f32x4 acc[4] = {};
  for (int kt = 0; kt < 16; ++kt){
    if (tid < 256)
      gload16(Abase + (size_t)(m0 + arow) * 1024 + kt * 64 + ((asub ^ (arow & 7)) << 3),
              &As[tid * 8]);
    #pragma unroll
    for (int i = 0; i < 4; ++i){
      int cc = i * 512 + tid;
      int r2 = cc >> 3, s2 = cc & 7;
      gload16(W1T + (size_t)r2 * 1024 + kt * 64 + ((s2 ^ (r2 & 7)) << 3), &Bs[cc * 8]);
    }
    VMW(0);
    BAR();
    #pragma unroll
    for (int ks = 0; ks < 2; ++ks){
      const int kb = ks * 64 + lq * 16;
      const int ra = rf * 16 + lr;
      bf16x8 af = *(const bf16x8*)((const char*)As + ra * 128 + (kb ^ ((ra & 7) << 4)));
      #pragma unroll
      for (int fc = 0; fc < 4; ++fc){
        int rb = ch * 64 + fc * 16 + lr;
        bf16x8 bf = *(const bf16x8*)((const char*)Bs + rb * 128 + (kb ^ ((rb & 7) << 4)));
        acc[fc] = __builtin_amdgcn_mfma_f32_16x16x32_bf16(af, bf, acc[fc], 0, 0, 0);
      }
    }
    BAR();
  }
  // hidden -> LDS (bias + relu + bf16), swizzled
  #pragma unroll
  for (int fc = 0; fc < 4; ++fc){
    int col = ch * 64 + fc * 16 + lr;
    float bv = b1[col];
    #pragma unroll
    for (int j = 0; j < 4; ++j){
      int rr = rf * 16 + lq * 4 + j;
      float v = fmaxf(acc[fc][j] + bv, 0.f);
      *(u16*)((char*)Hs + rr * 512 + ((col * 2) ^ ((rr & 7) << 4))) = f2b(v);
    }
  }
  __syncthreads();
  // layer 2: [32,256] @ W2T[64,256]^T -> [32,64]
  const int rf2 = w & 1, cp = w >> 1;
  f32x4 acc2 = {};
  #pragma unroll
  for (int ks2 = 0; ks2 < 8; ++ks2){
    int rr = rf2 * 16 + lr;
    int kb2 = ks2 * 64 + lq * 16;
    bf16x8 af2 = *(const bf16x8*)((const char*)Hs + rr * 512 + (kb2 ^ ((rr & 7) << 4)));
    bf16x8 w2 = *(const bf16x8*)(W2T + (size_t)(cp * 16 + lr) * 256 + ks2 * 32 + lq * 8);
    acc2 = __builtin_amdgcn_mfma_f32_16x16x32_bf16(af2, w2, acc2, 0, 0, 0);
  }
  {
    int col = cp * 16 + lr;
    float bv = b2[col];
    #pragma unroll
    for (int j = 0; j < 4; ++j){
      int rr = m0 + rf2 * 16 + lq * 4 + j;
      Obase[(size_t)rr * 64 + col] = acc2[j] + bv;
    }
  }
  __syncthreads();
  }
}

// =================== k_mixgru (x REP): mix + GRU, 512 blocks x 32 rows ======
__global__ __launch_bounds__(512, 4) void k_mixgru(
    const u16* __restrict__ qb, const u8* __restrict__ cb8,
    const float* __restrict__ qn, const float* __restrict__ cn,
    const int* __restrict__ rci, const int* __restrict__ filt,
    const float* __restrict__ redq, const float* __restrict__ redc,
    const float* __restrict__ h, const float* __restrict__ emb,
    const float* __restrict__ op, const float* __restrict__ Wp,
    const float* __restrict__ bp, const u16* __restrict__ WxhT,
    const float* __restrict__ bxh, float* __restrict__ prob_out,
    float* __restrict__ outh)
{
  __shared__ u16 XH[32 * 320];     // 20 KB, row stride 640 B, XOR-swizzled
  __shared__ u16 Bs[256 * 64];     // 32 KB
  const int tid = threadIdx.x;
  const int lane = tid & 63;
  const int w = tid >> 6;
  const int m0 = blockIdx.x << 5;

  auto stageB = [&](int kt){
    #pragma unroll
    for (int i = 0; i < 4; ++i){
      int cc = i * 512 + tid;
      int r2 = cc >> 3, s2 = cc & 7;
      gload16(WxhT + (size_t)r2 * 320 + kt * 64 + ((s2 ^ (r2 & 7)) << 3), &Bs[cc * 8]);
    }
  };

  for (int rep = 0; rep < REP; ++rep){
  CLOBBER();
  stageB(0);   // flies under the mix phase

  // ---------------- mix phase: 4 rows per wave ----------------
  for (int i = 0; i < 4; ++i){
    const int r = w * 4 + i;
    const int b = m0 + r;
    const u16* qrow = qb + (size_t)b * TDIM_ + lane * 16;
    u16x8 qa = *(const u16x8*)qrow;
    u16x8 qc = *(const u16x8*)(qrow + 8);
    float qf[16];
    #pragma unroll
    for (int k = 0; k < 8; ++k){ qf[k] = b2f(qa[k]); qf[8 + k] = b2f(qc[k]); }
    int idxm[MAXC_];
    #pragma unroll
    for (int m = 0; m < MAXC_; ++m) idxm[m] = rci[b * MAXC_ + m];
    float dots[MAXC_];
    #pragma unroll
    for (int m = 0; m < MAXC_; ++m){
      uint4 cw = *(const uint4*)(cb8 + (size_t)idxm[m] * TDIM_ + lane * 16);
      float s = 0.f; f32x2 p;
      p = unpk_fp8<false>(cw.x); s += qf[0]*p[0]  + qf[1]*p[1];
      p = unpk_fp8<true >(cw.x); s += qf[2]*p[0]  + qf[3]*p[1];
      p = unpk_fp8<false>(cw.y); s += qf[4]*p[0]  + qf[5]*p[1];
      p = unpk_fp8<true >(cw.y); s += qf[6]*p[0]  + qf[7]*p[1];
      p = unpk_fp8<false>(cw.z); s += qf[8]*p[0]  + qf[9]*p[1];
      p = unpk_fp8<true >(cw.z); s += qf[10]*p[0] + qf[11]*p[1];
      p = unpk_fp8<false>(cw.w); s += qf[12]*p[0] + qf[13]*p[1];
      p = unpk_fp8<true >(cw.w); s += qf[14]*p[0] + qf[15]*p[1];
      dots[m] = s;
    }
    #pragma unroll
    for (int o = 32; o; o >>= 1){
      #pragma unroll
      for (int m = 0; m < MAXC_; ++m) dots[m] += __shfl_xor(dots[m], o);
    }
    const float qnb = qn[b];
    float sv[MAXC_]; float mx = -3.0e38f;
    #pragma unroll
    for (int m = 0; m < MAXC_; ++m){
      float dnm = fmaxf(qnb * cn[idxm[m]], 1e-8f);
      float s = (filt[b * MAXC_ + m] == 0) ? -1e9f : dots[m] * (1.f / 32.f) / dnm;
      sv[m] = s; mx = fmaxf(mx, s);
    }
    float se = 0.f;
    #pragma unroll
    for (int m = 0; m < MAXC_; ++m){ sv[m] = __expf(sv[m] - mx); se += sv[m]; }
    const float inv = 1.f / se;
    float rep2 = 0.f;
    #pragma unroll
    for (int m = 0; m < MAXC_; ++m) rep2 += sv[m] * redc[(size_t)idxm[m] * D_ + lane];
    rep2 *= inv;
    const float v0 = redq[(size_t)b * D_ + lane];
    const float hv = h[(size_t)b * D_ + lane];
    const float e0 = emb[(size_t)b * 128 + lane];
    const float e1 = emb[(size_t)b * 128 + 64 + lane];
    float p = hv * Wp[lane] + v0 * Wp[64 + lane] + rep2 * Wp[128 + lane]
            + e0 * Wp[192 + lane] + e1 * Wp[256 + lane];
    p = wsum(p);
    if (lane == 0) prob_out[b] = p + bp[0];
    const float o = op[b], om = 1.f - o;
    auto xst = [&](int col, float v){
      *(u16*)((char*)XH + r * 640 + ((col * 2) ^ ((r & 7) << 4))) = f2b(v);
    };
    xst(lane,        v0 * o  + e0 * om);
    xst(64 + lane,   rep2 * o + e1 * om);
    xst(128 + lane,  v0 * om + e0 * o);
    xst(192 + lane,  rep2 * om + e1 * o);
    xst(256 + lane,  hv);
  }
  __syncthreads();

  // ---------------- GRU GEMM: [32,320]@[320,256], wave tile 16x64 ----------
  const int lr = lane & 15, lq = lane >> 4;
  const int rh = w & 1, cc = w >> 1;
  f32x4 acc[4] = {};
  for (int kt = 0; kt < 5; ++kt){
    VMW(0);
    BAR();
    #pragma unroll
    for (int ks = 0; ks < 2; ++ks){
      const int kb = ks * 64 + lq * 16;
      int rra = rh * 16 + lr;
      bf16x8 af = *(const bf16x8*)((const char*)XH + rra * 640 +
                                   ((kt * 128 + kb) ^ ((rra & 7) << 4)));
      bf16x8 bfr[4];
      #pragma unroll
      for (int fc = 0; fc < 4; ++fc){
        int rr = cc * 64 + fc * 16 + lr;
        bfr[fc] = *(const bf16x8*)((const char*)Bs + rr * 128 + (kb ^ ((rr & 7) << 4)));
      }
      #pragma unroll
      for (int fc = 0; fc < 4; ++fc)
        acc[fc] = __builtin_amdgcn_mfma_f32_16x16x32_bf16(af, bfr[fc], acc[fc], 0, 0, 0);
    }
    BAR();
    if (kt < 4) stageB(kt + 1);
  }
  const int d = cc * 16 + lr;
  float bg[4];
  #pragma unroll
  for (int g = 0; g < 4; ++g) bg[g] = bxh[cc * 64 + g * 16 + lr];
  #pragma unroll
  for (int j = 0; j < 4; ++j){
    float rv = sigf(acc[0][j] + bg[0]);
    float zv = sigf(acc[1][j] + bg[1]);
    float nv = tanhf(acc[2][j] + bg[2] + rv * (acc[3][j] + bg[3]));
    int rr = m0 + rh * 16 + lq * 4 + j;
    float hv = h[(size_t)rr * 64 + d];
    outh[(size_t)rr * 64 + d] = (1.f - zv) * nv + zv * hv;
  }
  __syncthreads();
  }
}

extern "C" void kernel_launch(void* const* d_in, const int* in_sizes, int n_in,
                              void* d_out, int out_size, void* d_ws, size_t ws_size,
                              hipStream_t stream) {
  const int*   prob_ids = (const int*)  d_in[0];
  const int*   rci      = (const int*)  d_in[1];
  const int*   filt     = (const int*)  d_in[2];
  const float* h        = (const float*)d_in[3];
  const float* emb      = (const float*)d_in[4];
  const float* op       = (const float*)d_in[5];
  const float* ex       = (const float*)d_in[6];
  const float* con      = (const float*)d_in[7];
  const float* W1       = (const float*)d_in[8];
  const float* b1       = (const float*)d_in[9];
  const float* W2       = (const float*)d_in[10];
  const float* b2       = (const float*)d_in[11];
  const float* Wp       = (const float*)d_in[12];
  const float* bp       = (const float*)d_in[13];
  const float* Wx       = (const float*)d_in[14];
  const float* Wh       = (const float*)d_in[15];
  const float* bx       = (const float*)d_in[16];
  const float* bh       = (const float*)d_in[17];
  float* out = (float*)d_out;

  char* w = (char*)d_ws;
  size_t off = 0;
  auto alloc = [&](size_t bytes){ size_t o = off; off = (off + bytes + 255) & ~(size_t)255; return o; };
  u16*   qb   = (u16*)  (w + alloc((size_t)B_ * TDIM_ * 2));      // 32 MB
  u16*   cb   = (u16*)  (w + alloc((size_t)NCONP_ * TDIM_ * 2));  // 4 MB
  u8*    cb8  = (u8*)   (w + alloc((size_t)NCONP_ * TDIM_));      // 2 MB
  float* qn   = (float*)(w + alloc((size_t)B_ * 4));
  float* cn   = (float*)(w + alloc((size_t)NCONP_ * 4));
  float* redq = (float*)(w + alloc((size_t)B_ * D_ * 4));         // 4 MB
  float* redc = (float*)(w + alloc((size_t)NCONP_ * D_ * 4));
  u16*   W1T  = (u16*)  (w + alloc((size_t)HID_ * TDIM_ * 2));
  u16*   W2T  = (u16*)  (w + alloc((size_t)D_ * HID_ * 2));
  u16*   WxhT = (u16*)  (w + alloc((size_t)256 * 320 * 2));
  float* bxh  = (float*)(w + alloc((size_t)256 * 4));

  k_prep<<<6017, 256, 0, stream>>>(ex, prob_ids, con, W1, W2, Wx, Wh, bx, bh,
                                   qb, qn, cb, cb8, cn, W1T, W2T, WxhT, bxh);
  k_mlp<<<576, 512, 0, stream>>>(qb, cb, W1T, b1, W2T, b2, redq, redc);
  k_mixgru<<<512, 512, 0, stream>>>(qb, cb8, qn, cn, rci, filt, redq, redc,
                                    h, emb, op, Wp, bp, WxhT, bxh, out, out + B_);
}

// Round 13
// 109.828 us; speedup vs baseline: 6.9512x; 6.9512x over previous
//
#include <hip/hip_runtime.h>
#include <cstdint>
#include <cstddef>

typedef unsigned short u16;
typedef unsigned char u8;
typedef __bf16 bf16x8 __attribute__((ext_vector_type(8)));
typedef float f32x4 __attribute__((ext_vector_type(4)));
typedef float f32x2 __attribute__((ext_vector_type(2)));
typedef u16 u16x4 __attribute__((ext_vector_type(4)));
typedef u16 u16x8 __attribute__((ext_vector_type(8)));

#define B_ 16384
#define D_ 64
#define MAXC_ 8
#define NCON_ 2000
#define NCONP_ 2048
#define TDIM_ 1024
#define HID_ 256

#define VMW(n) asm volatile("s_waitcnt vmcnt(" #n ")" ::: "memory")
#define BAR() __builtin_amdgcn_s_barrier()

__device__ inline u16 f2b(float f){
  unsigned u = __float_as_uint(f);
  u += 0x7fffu + ((u >> 16) & 1u);
  return (u16)(u >> 16);
}
__device__ inline float b2f(u16 u){ return __uint_as_float(((unsigned)u) << 16); }

__device__ inline unsigned pk2fp8(float a, float b){
  return (unsigned)__builtin_amdgcn_cvt_pk_fp8_f32(a, b, 0, false);
}
template<bool HI>
__device__ inline f32x2 unpk_fp8(unsigned v){
  return __builtin_amdgcn_cvt_pk_f32_fp8(v, HI);
}

__device__ inline void gload16(const void* g, void* l){
  __builtin_amdgcn_global_load_lds((const __attribute__((address_space(1))) unsigned*)g,
                                   (__attribute__((address_space(3))) unsigned*)l, 16, 0, 0);
}

__device__ inline float wsum(float v){
  #pragma unroll
  for (int o = 32; o; o >>= 1) v += __shfl_xor(v, o);
  return v;
}
__device__ inline float sigf(float x){ return 1.f / (1.f + __expf(-x)); }

// =================== k_prep (exact R8) ======================================
// [0,4096): q gather -> qb(bf16)+qn ; [4096,4608): concepts -> cb,cb8,cn ;
// [4608,6017): weights
__global__ __launch_bounds__(256) void k_prep(
    const float* __restrict__ ex, const int* __restrict__ pid,
    const float* __restrict__ con,
    const float* __restrict__ W1, const float* __restrict__ W2,
    const float* __restrict__ Wx, const float* __restrict__ Wh,
    const float* __restrict__ bx, const float* __restrict__ bh,
    u16* __restrict__ qb, float* __restrict__ qn,
    u16* __restrict__ cb, u8* __restrict__ cb8, float* __restrict__ cn,
    u16* __restrict__ W1T, u16* __restrict__ W2T, u16* __restrict__ WxhT,
    float* __restrict__ bxh)
{
  const int bid = blockIdx.x, tid = threadIdx.x;
  const int lane = tid & 63;
  if (bid < 4096){                                  // ---- q gather ----
    const int b = bid * 4 + (tid >> 6);
    const float* src = ex + (size_t)pid[b] * TDIM_;
    u16* dst = qb + (size_t)b * TDIM_;
    float ss = 0.f;
    #pragma unroll
    for (int c = 0; c < 4; ++c){
      float4 v = *(const float4*)(src + c * 256 + lane * 4);
      ss += v.x*v.x + v.y*v.y + v.z*v.z + v.w*v.w;
      u16x4 o = { f2b(v.x), f2b(v.y), f2b(v.z), f2b(v.w) };
      *(u16x4*)(dst + c * 256 + lane * 4) = o;
    }
    ss = wsum(ss);
    if (lane == 0) qn[b] = sqrtf(ss);
  } else if (bid < 4608){                           // ---- concepts ----
    const int r = (bid - 4096) * 4 + (tid >> 6);
    u16* dst = cb + (size_t)r * TDIM_;
    u8*  dst8 = cb8 + (size_t)r * TDIM_;
    if (r < NCON_){
      const float* src = con + (size_t)r * TDIM_;
      float ss = 0.f;
      #pragma unroll
      for (int c = 0; c < 4; ++c){
        float4 v = *(const float4*)(src + c * 256 + lane * 4);
        ss += v.x*v.x + v.y*v.y + v.z*v.z + v.w*v.w;
        u16x4 o = { f2b(v.x), f2b(v.y), f2b(v.z), f2b(v.w) };
        *(u16x4*)(dst + c * 256 + lane * 4) = o;
        unsigned lo = pk2fp8(v.x * 32.f, v.y * 32.f);
        unsigned hi = pk2fp8(v.z * 32.f, v.w * 32.f);
        *(unsigned*)(dst8 + c * 256 + lane * 4) = (lo & 0xffffu) | (hi << 16);
      }
      ss = wsum(ss);
      if (lane == 0) cn[r] = sqrtf(ss);
    } else {
      u16x4 z = { 0, 0, 0, 0 };
      #pragma unroll
      for (int c = 0; c < 4; ++c){
        *(u16x4*)(dst + c * 256 + lane * 4) = z;
        *(unsigned*)(dst8 + c * 256 + lane * 4) = 0u;
      }
    }
  } else {                                          // ---- weights ----
    int gid = (bid - 4608) * 256 + tid;
    if (gid < 262144){                       // W1T: n*1024 + k
      int n = gid >> 10, k = gid & 1023;
      W1T[gid] = f2b(W1[(size_t)k * 256 + n]);
    } else if (gid < 278528){                // W2T: n*256 + k
      int t = gid - 262144;
      int n = t >> 8, k = t & 255;
      W2T[t] = f2b(W2[(size_t)k * 64 + n]);
    } else if (gid < 360448){                // WxhT: c*320 + k, gate-interleaved
      int t = gid - 278528;
      int c = t / 320, k = t % 320;
      int g = (c >> 4) & 3;
      int d = (c >> 6) * 16 + (c & 15);
      float v = 0.f;
      if (k < 256){
        if (g == 0)      v = Wx[(size_t)k * 192 + d];
        else if (g == 1) v = Wx[(size_t)k * 192 + 64 + d];
        else if (g == 2) v = Wx[(size_t)k * 192 + 128 + d];
      } else {
        int kh = k - 256;
        if (g == 0)      v = Wh[(size_t)kh * 192 + d];
        else if (g == 1) v = Wh[(size_t)kh * 192 + 64 + d];
        else if (g == 3) v = Wh[(size_t)kh * 192 + 128 + d];
      }
      WxhT[t] = f2b(v);
    } else if (gid < 360704){                // bxh
      int c = gid - 360448;
      int g = (c >> 4) & 3;
      int d = (c >> 6) * 16 + (c & 15);
      float v;
      if (g == 0)      v = bx[d] + bh[d];
      else if (g == 1) v = bx[64 + d] + bh[64 + d];
      else if (g == 2) v = bx[128 + d];
      else             v = bh[128 + d];
      bxh[c] = v;
    }
  }
}

// =================== k_mlp (exact R8): red = relu(A@W1+b1)@W2+b2 ============
// BM=32, 576 blocks x 512 thr (blocks [0,512): q rows; [512,576): c rows).
__global__ __launch_bounds__(512) void k_mlp(
    const u16* __restrict__ qb, const u16* __restrict__ cb,
    const u16* __restrict__ W1T, const float* __restrict__ b1,
    const u16* __restrict__ W2T, const float* __restrict__ b2,
    float* __restrict__ redq, float* __restrict__ redc)
{
  __shared__ u16 As[32 * 64];      // 4 KB
  __shared__ u16 Bs[256 * 64];     // 32 KB
  __shared__ u16 Hs[32 * 256];     // 16 KB
  const int tid = threadIdx.x;
  const int lane = tid & 63;
  const int w = tid >> 6;
  const int lr = lane & 15, lq = lane >> 4;
  const bool qside = blockIdx.x < 512;
  const u16* Abase = qside ? qb : cb;
  float* Obase = qside ? redq : redc;
  const int m0 = (qside ? (int)blockIdx.x : ((int)blockIdx.x - 512)) << 5;
  const int rf = w & 1, ch = w >> 1;
  const int arow = tid >> 3, asub = tid & 7;

  f32x4 acc[4] = {};
  for (int kt = 0; kt < 16; ++kt){
    if (tid < 256)
      gload16(Abase + (size_t)(m0 + arow) * 1024 + kt * 64 + ((asub ^ (arow & 7)) << 3),
              &As[tid * 8]);
    #pragma unroll
    for (int i = 0; i < 4; ++i){
      int cc = i * 512 + tid;
      int r2 = cc >> 3, s2 = cc & 7;
      gload16(W1T + (size_t)r2 * 1024 + kt * 64 + ((s2 ^ (r2 & 7)) << 3), &Bs[cc * 8]);
    }
    VMW(0);
    BAR();
    #pragma unroll
    for (int ks = 0; ks < 2; ++ks){
      const int kb = ks * 64 + lq * 16;
      const int ra = rf * 16 + lr;
      bf16x8 af = *(const bf16x8*)((const char*)As + ra * 128 + (kb ^ ((ra & 7) << 4)));
      #pragma unroll
      for (int fc = 0; fc < 4; ++fc){
        int rb = ch * 64 + fc * 16 + lr;
        bf16x8 bf = *(const bf16x8*)((const char*)Bs + rb * 128 + (kb ^ ((rb & 7) << 4)));
        acc[fc] = __builtin_amdgcn_mfma_f32_16x16x32_bf16(af, bf, acc[fc], 0, 0, 0);
      }
    }
    BAR();
  }
  // hidden -> LDS (bias + relu + bf16), swizzled
  #pragma unroll
  for (int fc = 0; fc < 4; ++fc){
    int col = ch * 64 + fc * 16 + lr;
    float bv = b1[col];
    #pragma unroll
    for (int j = 0; j < 4; ++j){
      int rr = rf * 16 + lq * 4 + j;
      float v = fmaxf(acc[fc][j] + bv, 0.f);
      *(u16*)((char*)Hs + rr * 512 + ((col * 2) ^ ((rr & 7) << 4))) = f2b(v);
    }
  }
  __syncthreads();
  // layer 2: [32,256] @ W2T[64,256]^T -> [32,64]
  const int rf2 = w & 1, cp = w >> 1;
  f32x4 acc2 = {};
  #pragma unroll
  for (int ks2 = 0; ks2 < 8; ++ks2){
    int rr = rf2 * 16 + lr;
    int kb2 = ks2 * 64 + lq * 16;
    bf16x8 af2 = *(const bf16x8*)((const char*)Hs + rr * 512 + (kb2 ^ ((rr & 7) << 4)));
    bf16x8 w2 = *(const bf16x8*)(W2T + (size_t)(cp * 16 + lr) * 256 + ks2 * 32 + lq * 8);
    acc2 = __builtin_amdgcn_mfma_f32_16x16x32_bf16(af2, w2, acc2, 0, 0, 0);
  }
  {
    int col = cp * 16 + lr;
    float bv = b2[col];
    #pragma unroll
    for (int j = 0; j < 4; ++j){
      int rr = m0 + rf2 * 16 + lq * 4 + j;
      Obase[(size_t)rr * 64 + col] = acc2[j] + bv;
    }
  }
}

// =================== k_mixgru: 1024 blocks x 16 rows, 3 blocks/CU ===========
__global__ __launch_bounds__(512, 6) void k_mixgru(
    const u16* __restrict__ qb, const u8* __restrict__ cb8,
    const float* __restrict__ qn, const float* __restrict__ cn,
    const int* __restrict__ rci, const int* __restrict__ filt,
    const float* __restrict__ redq, const float* __restrict__ redc,
    const float* __restrict__ h, const float* __restrict__ emb,
    const float* __restrict__ op, const float* __restrict__ Wp,
    const float* __restrict__ bp, const u16* __restrict__ WxhT,
    const float* __restrict__ bxh, float* __restrict__ prob_out,
    float* __restrict__ outh)
{
  __shared__ u16 XH[16 * 320];     // 10 KB, row stride 640 B, XOR-swizzled
  __shared__ u16 Bs[256 * 64];     // 32 KB
  __shared__ int IDX[16 * MAXC_];  // 512 B prefetched rci
  __shared__ int FLT[16 * MAXC_];  // 512 B prefetched filter
  const int tid = threadIdx.x;
  const int lane = tid & 63;
  const int w = tid >> 6;
  const int m0 = blockIdx.x << 4;

  auto stageB = [&](int kt){
    #pragma unroll
    for (int i = 0; i < 4; ++i){
      int cc = i * 512 + tid;
      int r2 = cc >> 3, s2 = cc & 7;
      gload16(WxhT + (size_t)r2 * 320 + kt * 64 + ((s2 ^ (r2 & 7)) << 3), &Bs[cc * 8]);
    }
  };
  // prefetch indices + first B tile; both fly under the mix phase start
  if (tid < 16 * MAXC_){
    IDX[tid] = rci[m0 * MAXC_ + tid];
    FLT[tid] = filt[m0 * MAXC_ + tid];
  }
  stageB(0);
  __syncthreads();   // IDX/FLT visible

  // ---------------- mix phase: 2 rows per wave ----------------
  for (int i = 0; i < 2; ++i){
    const int r = w * 2 + i;
    const int b = m0 + r;
    const u16* qrow = qb + (size_t)b * TDIM_ + lane * 16;
    u16x8 qa = *(const u16x8*)qrow;
    u16x8 qc = *(const u16x8*)(qrow + 8);
    float qf[16];
    #pragma unroll
    for (int k = 0; k < 8; ++k){ qf[k] = b2f(qa[k]); qf[8 + k] = b2f(qc[k]); }
    int idxm[MAXC_];
    #pragma unroll
    for (int m = 0; m < MAXC_; ++m) idxm[m] = IDX[r * MAXC_ + m];
    float dots[MAXC_];
    #pragma unroll
    for (int m = 0; m < MAXC_; ++m){
      uint4 cw = *(const uint4*)(cb8 + (size_t)idxm[m] * TDIM_ + lane * 16);
      float s = 0.f; f32x2 p;
      p = unpk_fp8<false>(cw.x); s += qf[0]*p[0]  + qf[1]*p[1];
      p = unpk_fp8<true >(cw.x); s += qf[2]*p[0]  + qf[3]*p[1];
      p = unpk_fp8<false>(cw.y); s += qf[4]*p[0]  + qf[5]*p[1];
      p = unpk_fp8<true >(cw.y); s += qf[6]*p[0]  + qf[7]*p[1];
      p = unpk_fp8<false>(cw.z); s += qf[8]*p[0]  + qf[9]*p[1];
      p = unpk_fp8<true >(cw.z); s += qf[10]*p[0] + qf[11]*p[1];
      p = unpk_fp8<false>(cw.w); s += qf[12]*p[0] + qf[13]*p[1];
      p = unpk_fp8<true >(cw.w); s += qf[14]*p[0] + qf[15]*p[1];
      dots[m] = s;
    }
    #pragma unroll
    for (int o = 32; o; o >>= 1){
      #pragma unroll
      for (int m = 0; m < MAXC_; ++m) dots[m] += __shfl_xor(dots[m], o);
    }
    const float qnb = qn[b];
    float sv[MAXC_]; float mx = -3.0e38f;
    #pragma unroll
    for (int m = 0; m < MAXC_; ++m){
      float dnm = fmaxf(qnb * cn[idxm[m]], 1e-8f);
      float s = (FLT[r * MAXC_ + m] == 0) ? -1e9f : dots[m] * (1.f / 32.f) / dnm;
      sv[m] = s; mx = fmaxf(mx, s);
    }
    float se = 0.f;
    #pragma unroll
    for (int m = 0; m < MAXC_; ++m){ sv[m] = __expf(sv[m] - mx); se += sv[m]; }
    const float inv = 1.f / se;
    float rep = 0.f;
    #pragma unroll
    for (int m = 0; m < MAXC_; ++m) rep += sv[m] * redc[(size_t)idxm[m] * D_ + lane];
    rep *= inv;
    const float v0 = redq[(size_t)b * D_ + lane];
    const float hv = h[(size_t)b * D_ + lane];
    const float e0 = emb[(size_t)b * 128 + lane];
    const float e1 = emb[(size_t)b * 128 + 64 + lane];
    float p = hv * Wp[lane] + v0 * Wp[64 + lane] + rep * Wp[128 + lane]
            + e0 * Wp[192 + lane] + e1 * Wp[256 + lane];
    p = wsum(p);
    if (lane == 0) prob_out[b] = p + bp[0];
    const float o = op[b], om = 1.f - o;
    auto xst = [&](int col, float v){
      *(u16*)((char*)XH + r * 640 + ((col * 2) ^ ((r & 7) << 4))) = f2b(v);
    };
    xst(lane,        v0 * o  + e0 * om);
    xst(64 + lane,   rep * o + e1 * om);
    xst(128 + lane,  v0 * om + e0 * o);
    xst(192 + lane,  rep * om + e1 * o);
    xst(256 + lane,  hv);
  }
  __syncthreads();

  // ---------------- GRU GEMM: [16,320]@[320,256]; waves 0-3 compute --------
  const int lr = lane & 15, lq = lane >> 4;
  f32x4 acc[4] = {};
  for (int kt = 0; kt < 5; ++kt){
    VMW(0);
    BAR();
    if (w < 4){
      #pragma unroll
      for (int ks = 0; ks < 2; ++ks){
        const int kb = ks * 64 + lq * 16;
        bf16x8 af = *(const bf16x8*)((const char*)XH + lr * 640 +
                                     ((kt * 128 + kb) ^ ((lr & 7) << 4)));
        #pragma unroll
        for (int fc = 0; fc < 4; ++fc){
          int rb = w * 64 + fc * 16 + lr;
          bf16x8 bf = *(const bf16x8*)((const char*)Bs + rb * 128 + (kb ^ ((rb & 7) << 4)));
          acc[fc] = __builtin_amdgcn_mfma_f32_16x16x32_bf16(af, bf, acc[fc], 0, 0, 0);
        }
      }
    }
    BAR();
    if (kt < 4) stageB(kt + 1);
  }
  if (w < 4){
    const int d = w * 16 + lr;
    float bg[4];
    #pragma unroll
    for (int g = 0; g < 4; ++g) bg[g] = bxh[w * 64 + g * 16 + lr];
    #pragma unroll
    for (int j = 0; j < 4; ++j){
      float rv = sigf(acc[0][j] + bg[0]);
      float zv = sigf(acc[1][j] + bg[1]);
      float nv = tanhf(acc[2][j] + bg[2] + rv * (acc[3][j] + bg[3]));
      int rr = m0 + lq * 4 + j;
      float hv = h[(size_t)rr * 64 + d];
      outh[(size_t)rr * 64 + d] = (1.f - zv) * nv + zv * hv;
    }
  }
}

extern "C" void kernel_launch(void* const* d_in, const int* in_sizes, int n_in,
                              void* d_out, int out_size, void* d_ws, size_t ws_size,
                              hipStream_t stream) {
  const int*   prob_ids = (const int*)  d_in[0];
  const int*   rci      = (const int*)  d_in[1];
  const int*   filt     = (const int*)  d_in[2];
  const float* h        = (const float*)d_in[3];
  const float* emb      = (const float*)d_in[4];
  const float* op       = (const float*)d_in[5];
  const float* ex       = (const float*)d_in[6];
  const float* con      = (const float*)d_in[7];
  const float* W1       = (const float*)d_in[8];
  const float* b1       = (const float*)d_in[9];
  const float* W2       = (const float*)d_in[10];
  const float* b2       = (const float*)d_in[11];
  const float* Wp       = (const float*)d_in[12];
  const float* bp       = (const float*)d_in[13];
  const float* Wx       = (const float*)d_in[14];
  const float* Wh       = (const float*)d_in[15];
  const float* bx       = (const float*)d_in[16];
  const float* bh       = (const float*)d_in[17];
  float* out = (float*)d_out;

  char* w = (char*)d_ws;
  size_t off = 0;
  auto alloc = [&](size_t bytes){ size_t o = off; off = (off + bytes + 255) & ~(size_t)255; return o; };
  u16*   qb   = (u16*)  (w + alloc((size_t)B_ * TDIM_ * 2));      // 32 MB
  u16*   cb   = (u16*)  (w + alloc((size_t)NCONP_ * TDIM_ * 2));  // 4 MB
  u8*    cb8  = (u8*)   (w + alloc((size_t)NCONP_ * TDIM_));      // 2 MB
  float* qn   = (float*)(w + alloc((size_t)B_ * 4));
  float* cn   = (float*)(w + alloc((size_t)NCONP_ * 4));
  float* redq = (float*)(w + alloc((size_t)B_ * D_ * 4));         // 4 MB
  float* redc = (float*)(w + alloc((size_t)NCONP_ * D_ * 4));
  u16*   W1T  = (u16*)  (w + alloc((size_t)HID_ * TDIM_ * 2));
  u16*   W2T  = (u16*)  (w + alloc((size_t)D_ * HID_ * 2));
  u16*   WxhT = (u16*)  (w + alloc((size_t)256 * 320 * 2));
  float* bxh  = (float*)(w + alloc((size_t)256 * 4));

  k_prep<<<6017, 256, 0, stream>>>(ex, prob_ids, con, W1, W2, Wx, Wh, bx, bh,
                                   qb, qn, cb, cb8, cn, W1T, W2T, WxhT, bxh);
  k_mlp<<<576, 512, 0, stream>>>(qb, cb, W1T, b1, W2T, b2, redq, redc);
  k_mixgru<<<1024, 512, 0, stream>>>(qb, cb8, qn, cn, rci, filt, redq, redc,
                                     h, emb, op, Wp, bp, WxhT, bxh, out, out + B_);
}

// Round 14
// 91.583 us; speedup vs baseline: 8.3359x; 1.1992x over previous
//
#include <hip/hip_runtime.h>
#include <cstdint>
#include <cstddef>

typedef unsigned short u16;
typedef unsigned char u8;
typedef __bf16 bf16x8 __attribute__((ext_vector_type(8)));
typedef float f32x4 __attribute__((ext_vector_type(4)));
typedef float f32x2 __attribute__((ext_vector_type(2)));
typedef u16 u16x4 __attribute__((ext_vector_type(4)));
typedef u16 u16x8 __attribute__((ext_vector_type(8)));

#define B_ 16384
#define D_ 64
#define MAXC_ 8
#define NCON_ 2000
#define NCONP_ 2048
#define TDIM_ 1024
#define HID_ 256

#define VMW(n) asm volatile("s_waitcnt vmcnt(" #n ")" ::: "memory")
#define BAR() __builtin_amdgcn_s_barrier()

__device__ inline u16 f2b(float f){
  unsigned u = __float_as_uint(f);
  u += 0x7fffu + ((u >> 16) & 1u);
  return (u16)(u >> 16);
}
__device__ inline float b2f(u16 u){ return __uint_as_float(((unsigned)u) << 16); }

__device__ inline unsigned pk2fp8(float a, float b){
  return (unsigned)__builtin_amdgcn_cvt_pk_fp8_f32(a, b, 0, false);
}
template<bool HI>
__device__ inline f32x2 unpk_fp8(unsigned v){
  return __builtin_amdgcn_cvt_pk_f32_fp8(v, HI);
}

__device__ inline void gload16(const void* g, void* l){
  __builtin_amdgcn_global_load_lds((const __attribute__((address_space(1))) unsigned*)g,
                                   (__attribute__((address_space(3))) unsigned*)l, 16, 0, 0);
}

__device__ inline float wsum(float v){
  #pragma unroll
  for (int o = 32; o; o >>= 1) v += __shfl_xor(v, o);
  return v;
}
__device__ inline float sigf(float x){ return 1.f / (1.f + __expf(-x)); }

// =================== k_prep (exact R8) ======================================
__global__ __launch_bounds__(256) void k_prep(
    const float* __restrict__ ex, const int* __restrict__ pid,
    const float* __restrict__ con,
    const float* __restrict__ W1, const float* __restrict__ W2,
    const float* __restrict__ Wx, const float* __restrict__ Wh,
    const float* __restrict__ bx, const float* __restrict__ bh,
    u16* __restrict__ qb, float* __restrict__ qn,
    u16* __restrict__ cb, u8* __restrict__ cb8, float* __restrict__ cn,
    u16* __restrict__ W1T, u16* __restrict__ W2T, u16* __restrict__ WxhT,
    float* __restrict__ bxh)
{
  const int bid = blockIdx.x, tid = threadIdx.x;
  const int lane = tid & 63;
  if (bid < 4096){                                  // ---- q gather ----
    const int b = bid * 4 + (tid >> 6);
    const float* src = ex + (size_t)pid[b] * TDIM_;
    u16* dst = qb + (size_t)b * TDIM_;
    float ss = 0.f;
    #pragma unroll
    for (int c = 0; c < 4; ++c){
      float4 v = *(const float4*)(src + c * 256 + lane * 4);
      ss += v.x*v.x + v.y*v.y + v.z*v.z + v.w*v.w;
      u16x4 o = { f2b(v.x), f2b(v.y), f2b(v.z), f2b(v.w) };
      *(u16x4*)(dst + c * 256 + lane * 4) = o;
    }
    ss = wsum(ss);
    if (lane == 0) qn[b] = sqrtf(ss);
  } else if (bid < 4608){                           // ---- concepts ----
    const int r = (bid - 4096) * 4 + (tid >> 6);
    u16* dst = cb + (size_t)r * TDIM_;
    u8*  dst8 = cb8 + (size_t)r * TDIM_;
    if (r < NCON_){
      const float* src = con + (size_t)r * TDIM_;
      float ss = 0.f;
      #pragma unroll
      for (int c = 0; c < 4; ++c){
        float4 v = *(const float4*)(src + c * 256 + lane * 4);
        ss += v.x*v.x + v.y*v.y + v.z*v.z + v.w*v.w;
        u16x4 o = { f2b(v.x), f2b(v.y), f2b(v.z), f2b(v.w) };
        *(u16x4*)(dst + c * 256 + lane * 4) = o;
        unsigned lo = pk2fp8(v.x * 32.f, v.y * 32.f);
        unsigned hi = pk2fp8(v.z * 32.f, v.w * 32.f);
        *(unsigned*)(dst8 + c * 256 + lane * 4) = (lo & 0xffffu) | (hi << 16);
      }
      ss = wsum(ss);
      if (lane == 0) cn[r] = sqrtf(ss);
    } else {
      u16x4 z = { 0, 0, 0, 0 };
      #pragma unroll
      for (int c = 0; c < 4; ++c){
        *(u16x4*)(dst + c * 256 + lane * 4) = z;
        *(unsigned*)(dst8 + c * 256 + lane * 4) = 0u;
      }
    }
  } else {                                          // ---- weights ----
    int gid = (bid - 4608) * 256 + tid;
    if (gid < 262144){                       // W1T: n*1024 + k
      int n = gid >> 10, k = gid & 1023;
      W1T[gid] = f2b(W1[(size_t)k * 256 + n]);
    } else if (gid < 278528){                // W2T: n*256 + k
      int t = gid - 262144;
      int n = t >> 8, k = t & 255;
      W2T[t] = f2b(W2[(size_t)k * 64 + n]);
    } else if (gid < 360448){                // WxhT: c*320 + k, gate-interleaved
      int t = gid - 278528;
      int c = t / 320, k = t % 320;
      int g = (c >> 4) & 3;
      int d = (c >> 6) * 16 + (c & 15);
      float v = 0.f;
      if (k < 256){
        if (g == 0)      v = Wx[(size_t)k * 192 + d];
        else if (g == 1) v = Wx[(size_t)k * 192 + 64 + d];
        else if (g == 2) v = Wx[(size_t)k * 192 + 128 + d];
      } else {
        int kh = k - 256;
        if (g == 0)      v = Wh[(size_t)kh * 192 + d];
        else if (g == 1) v = Wh[(size_t)kh * 192 + 64 + d];
        else if (g == 3) v = Wh[(size_t)kh * 192 + 128 + d];
      }
      WxhT[t] = f2b(v);
    } else if (gid < 360704){                // bxh
      int c = gid - 360448;
      int g = (c >> 4) & 3;
      int d = (c >> 6) * 16 + (c & 15);
      float v;
      if (g == 0)      v = bx[d] + bh[d];
      else if (g == 1) v = bx[64 + d] + bh[64 + d];
      else if (g == 2) v = bx[128 + d];
      else             v = bh[128 + d];
      bxh[c] = v;
    }
  }
}

// =================== k_mlp (exact R8): red = relu(A@W1+b1)@W2+b2 ============
__global__ __launch_bounds__(512) void k_mlp(
    const u16* __restrict__ qb, const u16* __restrict__ cb,
    const u16* __restrict__ W1T, const float* __restrict__ b1,
    const u16* __restrict__ W2T, const float* __restrict__ b2,
    float* __restrict__ redq, float* __restrict__ redc)
{
  __shared__ u16 As[32 * 64];      // 4 KB
  __shared__ u16 Bs[256 * 64];     // 32 KB
  __shared__ u16 Hs[32 * 256];     // 16 KB
  const int tid = threadIdx.x;
  const int lane = tid & 63;
  const int w = tid >> 6;
  const int lr = lane & 15, lq = lane >> 4;
  const bool qside = blockIdx.x < 512;
  const u16* Abase = qside ? qb : cb;
  float* Obase = qside ? redq : redc;
  const int m0 = (qside ? (int)blockIdx.x : ((int)blockIdx.x - 512)) << 5;
  const int rf = w & 1, ch = w >> 1;
  const int arow = tid >> 3, asub = tid & 7;

  f32x4 acc[4] = {};
  for (int kt = 0; kt < 16; ++kt){
    if (tid < 256)
      gload16(Abase + (size_t)(m0 + arow) * 1024 + kt * 64 + ((asub ^ (arow & 7)) << 3),
              &As[tid * 8]);
    #pragma unroll
    for (int i = 0; i < 4; ++i){
      int cc = i * 512 + tid;
      int r2 = cc >> 3, s2 = cc & 7;
      gload16(W1T + (size_t)r2 * 1024 + kt * 64 + ((s2 ^ (r2 & 7)) << 3), &Bs[cc * 8]);
    }
    VMW(0);
    BAR();
    #pragma unroll
    for (int ks = 0; ks < 2; ++ks){
      const int kb = ks * 64 + lq * 16;
      const int ra = rf * 16 + lr;
      bf16x8 af = *(const bf16x8*)((const char*)As + ra * 128 + (kb ^ ((ra & 7) << 4)));
      #pragma unroll
      for (int fc = 0; fc < 4; ++fc){
        int rb = ch * 64 + fc * 16 + lr;
        bf16x8 bf = *(const bf16x8*)((const char*)Bs + rb * 128 + (kb ^ ((rb & 7) << 4)));
        acc[fc] = __builtin_amdgcn_mfma_f32_16x16x32_bf16(af, bf, acc[fc], 0, 0, 0);
      }
    }
    BAR();
  }
  #pragma unroll
  for (int fc = 0; fc < 4; ++fc){
    int col = ch * 64 + fc * 16 + lr;
    float bv = b1[col];
    #pragma unroll
    for (int j = 0; j < 4; ++j){
      int rr = rf * 16 + lq * 4 + j;
      float v = fmaxf(acc[fc][j] + bv, 0.f);
      *(u16*)((char*)Hs + rr * 512 + ((col * 2) ^ ((rr & 7) << 4))) = f2b(v);
    }
  }
  __syncthreads();
  const int rf2 = w & 1, cp = w >> 1;
  f32x4 acc2 = {};
  #pragma unroll
  for (int ks2 = 0; ks2 < 8; ++ks2){
    int rr = rf2 * 16 + lr;
    int kb2 = ks2 * 64 + lq * 16;
    bf16x8 af2 = *(const bf16x8*)((const char*)Hs + rr * 512 + (kb2 ^ ((rr & 7) << 4)));
    bf16x8 w2 = *(const bf16x8*)(W2T + (size_t)(cp * 16 + lr) * 256 + ks2 * 32 + lq * 8);
    acc2 = __builtin_amdgcn_mfma_f32_16x16x32_bf16(af2, w2, acc2, 0, 0, 0);
  }
  {
    int col = cp * 16 + lr;
    float bv = b2[col];
    #pragma unroll
    for (int j = 0; j < 4; ++j){
      int rr = m0 + rf2 * 16 + lq * 4 + j;
      Obase[(size_t)rr * 64 + col] = acc2[j] + bv;
    }
  }
}

// =================== k_mixgru: R8 geometry + latency-hiding mix =============
// 512 blocks x 32 rows x 512 thr. All per-row loads hoisted/pipelined.
__global__ __launch_bounds__(512) void k_mixgru(
    const u16* __restrict__ qb, const u8* __restrict__ cb8,
    const float* __restrict__ qn, const float* __restrict__ cn,
    const int* __restrict__ rci, const int* __restrict__ filt,
    const float* __restrict__ redq, const float* __restrict__ redc,
    const float* __restrict__ h, const float* __restrict__ emb,
    const float* __restrict__ op, const float* __restrict__ Wp,
    const float* __restrict__ bp, const u16* __restrict__ WxhT,
    const float* __restrict__ bxh, float* __restrict__ prob_out,
    float* __restrict__ outh)
{
  __shared__ u16 XH[32 * 320];     // 20 KB, row stride 640 B, XOR-swizzled
  __shared__ u16 Bs[256 * 64];     // 32 KB
  __shared__ int IDX[32 * MAXC_];  // 1 KB
  __shared__ int FLT[32 * MAXC_];  // 1 KB
  const int tid = threadIdx.x;
  const int lane = tid & 63;
  const int w = tid >> 6;
  const int m0 = blockIdx.x << 5;

  auto stageB = [&](int kt){
    #pragma unroll
    for (int i = 0; i < 4; ++i){
      int cc = i * 512 + tid;
      int r2 = cc >> 3, s2 = cc & 7;
      gload16(WxhT + (size_t)r2 * 320 + kt * 64 + ((s2 ^ (r2 & 7)) << 3), &Bs[cc * 8]);
    }
  };

  // ---- entry: issue ALL independent loads at once ----
  if (tid < 256) IDX[tid] = rci[m0 * MAXC_ + tid];
  else           FLT[tid - 256] = filt[m0 * MAXC_ + (tid - 256)];
  stageB(0);

  u16x8 qa[4], qc[4];
  float v0r[4], hvr[4], e0r[4], e1r[4], qnr[4], opr[4];
  #pragma unroll
  for (int i = 0; i < 4; ++i){
    const int b = m0 + w * 4 + i;
    const u16* qrow = qb + (size_t)b * TDIM_ + lane * 16;
    qa[i] = *(const u16x8*)qrow;
    qc[i] = *(const u16x8*)(qrow + 8);
    v0r[i] = redq[(size_t)b * D_ + lane];
    hvr[i] = h[(size_t)b * D_ + lane];
    e0r[i] = emb[(size_t)b * 128 + lane];
    e1r[i] = emb[(size_t)b * 128 + 64 + lane];
    qnr[i] = qn[b];
    opr[i] = op[b];
  }
  const float wp0 = Wp[lane], wp1 = Wp[64 + lane], wp2 = Wp[128 + lane],
              wp3 = Wp[192 + lane], wp4 = Wp[256 + lane];
  const float bp0 = bp[0];
  __syncthreads();   // IDX/FLT visible

  // ---- row 0 gathers ----
  int idxc[MAXC_], flc[MAXC_]; uint4 cwc[MAXC_]; float rcc[MAXC_], cnc[MAXC_];
  #pragma unroll
  for (int m = 0; m < MAXC_; ++m){
    idxc[m] = IDX[(w * 4) * MAXC_ + m];
    flc[m]  = FLT[(w * 4) * MAXC_ + m];
  }
  #pragma unroll
  for (int m = 0; m < MAXC_; ++m){
    cwc[m] = *(const uint4*)(cb8 + (size_t)idxc[m] * TDIM_ + lane * 16);
    rcc[m] = redc[(size_t)idxc[m] * D_ + lane];
    cnc[m] = cn[idxc[m]];
  }

  #pragma unroll
  for (int i = 0; i < 4; ++i){
    const int r = w * 4 + i;
    const int b = m0 + r;
    // issue next row's gathers before this row's reduce chain
    int idxn[MAXC_], fln[MAXC_]; uint4 cwn[MAXC_]; float rcn[MAXC_], cnn[MAXC_];
    if (i < 3){
      #pragma unroll
      for (int m = 0; m < MAXC_; ++m){
        idxn[m] = IDX[(r + 1) * MAXC_ + m];
        fln[m]  = FLT[(r + 1) * MAXC_ + m];
      }
      #pragma unroll
      for (int m = 0; m < MAXC_; ++m){
        cwn[m] = *(const uint4*)(cb8 + (size_t)idxn[m] * TDIM_ + lane * 16);
        rcn[m] = redc[(size_t)idxn[m] * D_ + lane];
        cnn[m] = cn[idxn[m]];
      }
    }
    // ---- compute row i ----
    float qf[16];
    #pragma unroll
    for (int k = 0; k < 8; ++k){ qf[k] = b2f(qa[i][k]); qf[8 + k] = b2f(qc[i][k]); }
    float dots[MAXC_];
    #pragma unroll
    for (int m = 0; m < MAXC_; ++m){
      float s = 0.f; f32x2 p;
      p = unpk_fp8<false>(cwc[m].x); s += qf[0]*p[0]  + qf[1]*p[1];
      p = unpk_fp8<true >(cwc[m].x); s += qf[2]*p[0]  + qf[3]*p[1];
      p = unpk_fp8<false>(cwc[m].y); s += qf[4]*p[0]  + qf[5]*p[1];
      p = unpk_fp8<true >(cwc[m].y); s += qf[6]*p[0]  + qf[7]*p[1];
      p = unpk_fp8<false>(cwc[m].z); s += qf[8]*p[0]  + qf[9]*p[1];
      p = unpk_fp8<true >(cwc[m].z); s += qf[10]*p[0] + qf[11]*p[1];
      p = unpk_fp8<false>(cwc[m].w); s += qf[12]*p[0] + qf[13]*p[1];
      p = unpk_fp8<true >(cwc[m].w); s += qf[14]*p[0] + qf[15]*p[1];
      dots[m] = s;
    }
    #pragma unroll
    for (int o = 32; o; o >>= 1){
      #pragma unroll
      for (int m = 0; m < MAXC_; ++m) dots[m] += __shfl_xor(dots[m], o);
    }
    float sv[MAXC_]; float mx = -3.0e38f;
    #pragma unroll
    for (int m = 0; m < MAXC_; ++m){
      float dnm = fmaxf(qnr[i] * cnc[m], 1e-8f);
      float s = (flc[m] == 0) ? -1e9f : dots[m] * (1.f / 32.f) / dnm;
      sv[m] = s; mx = fmaxf(mx, s);
    }
    float se = 0.f;
    #pragma unroll
    for (int m = 0; m < MAXC_; ++m){ sv[m] = __expf(sv[m] - mx); se += sv[m]; }
    const float inv = 1.f / se;
    float rep = 0.f;
    #pragma unroll
    for (int m = 0; m < MAXC_; ++m) rep += sv[m] * rcc[m];
    rep *= inv;
    const float v0 = v0r[i], hv = hvr[i], e0 = e0r[i], e1 = e1r[i];
    float p = hv * wp0 + v0 * wp1 + rep * wp2 + e0 * wp3 + e1 * wp4;
    p = wsum(p);
    if (lane == 0) prob_out[b] = p + bp0;
    const float o = opr[i], om = 1.f - o;
    auto xst = [&](int col, float v){
      *(u16*)((char*)XH + r * 640 + ((col * 2) ^ ((r & 7) << 4))) = f2b(v);
    };
    xst(lane,        v0 * o  + e0 * om);
    xst(64 + lane,   rep * o + e1 * om);
    xst(128 + lane,  v0 * om + e0 * o);
    xst(192 + lane,  rep * om + e1 * o);
    xst(256 + lane,  hv);
    // rotate pipeline registers (renamed away by unroll)
    if (i < 3){
      #pragma unroll
      for (int m = 0; m < MAXC_; ++m){
        idxc[m] = idxn[m]; flc[m] = fln[m];
        cwc[m] = cwn[m]; rcc[m] = rcn[m]; cnc[m] = cnn[m];
      }
    }
  }
  __syncthreads();

  // ---------------- GRU GEMM: [32,320]@[320,256], wave tile 16x64 ----------
  const int lr = lane & 15, lq = lane >> 4;
  const int rh = w & 1, cc = w >> 1;
  f32x4 acc[4] = {};
  for (int kt = 0; kt < 5; ++kt){
    VMW(0);
    BAR();
    #pragma unroll
    for (int ks = 0; ks < 2; ++ks){
      const int kb = ks * 64 + lq * 16;
      int rra = rh * 16 + lr;
      bf16x8 af = *(const bf16x8*)((const char*)XH + rra * 640 +
                                   ((kt * 128 + kb) ^ ((rra & 7) << 4)));
      bf16x8 bfr[4];
      #pragma unroll
      for (int fc = 0; fc < 4; ++fc){
        int rr = cc * 64 + fc * 16 + lr;
        bfr[fc] = *(const bf16x8*)((const char*)Bs + rr * 128 + (kb ^ ((rr & 7) << 4)));
      }
      #pragma unroll
      for (int fc = 0; fc < 4; ++fc)
        acc[fc] = __builtin_amdgcn_mfma_f32_16x16x32_bf16(af, bfr[fc], acc[fc], 0, 0, 0);
    }
    BAR();
    if (kt < 4) stageB(kt + 1);
  }
  const int d = cc * 16 + lr;
  float bg[4];
  #pragma unroll
  for (int g = 0; g < 4; ++g) bg[g] = bxh[cc * 64 + g * 16 + lr];
  #pragma unroll
  for (int j = 0; j < 4; ++j){
    float rv = sigf(acc[0][j] + bg[0]);
    float zv = sigf(acc[1][j] + bg[1]);
    float nv = tanhf(acc[2][j] + bg[2] + rv * (acc[3][j] + bg[3]));
    int rr = m0 + rh * 16 + lq * 4 + j;
    float hv = h[(size_t)rr * 64 + d];
    outh[(size_t)rr * 64 + d] = (1.f - zv) * nv + zv * hv;
  }
}

extern "C" void kernel_launch(void* const* d_in, const int* in_sizes, int n_in,
                              void* d_out, int out_size, void* d_ws, size_t ws_size,
                              hipStream_t stream) {
  const int*   prob_ids = (const int*)  d_in[0];
  const int*   rci      = (const int*)  d_in[1];
  const int*   filt     = (const int*)  d_in[2];
  const float* h        = (const float*)d_in[3];
  const float* emb      = (const float*)d_in[4];
  const float* op       = (const float*)d_in[5];
  const float* ex       = (const float*)d_in[6];
  const float* con      = (const float*)d_in[7];
  const float* W1       = (const float*)d_in[8];
  const float* b1       = (const float*)d_in[9];
  const float* W2       = (const float*)d_in[10];
  const float* b2       = (const float*)d_in[11];
  const float* Wp       = (const float*)d_in[12];
  const float* bp       = (const float*)d_in[13];
  const float* Wx       = (const float*)d_in[14];
  const float* Wh       = (const float*)d_in[15];
  const float* bx       = (const float*)d_in[16];
  const float* bh       = (const float*)d_in[17];
  float* out = (float*)d_out;

  char* w = (char*)d_ws;
  size_t off = 0;
  auto alloc = [&](size_t bytes){ size_t o = off; off = (off + bytes + 255) & ~(size_t)255; return o; };
  u16*   qb   = (u16*)  (w + alloc((size_t)B_ * TDIM_ * 2));      // 32 MB
  u16*   cb   = (u16*)  (w + alloc((size_t)NCONP_ * TDIM_ * 2));  // 4 MB
  u8*    cb8  = (u8*)   (w + alloc((size_t)NCONP_ * TDIM_));      // 2 MB
  float* qn   = (float*)(w + alloc((size_t)B_ * 4));
  float* cn   = (float*)(w + alloc((size_t)NCONP_ * 4));
  float* redq = (float*)(w + alloc((size_t)B_ * D_ * 4));         // 4 MB
  float* redc = (float*)(w + alloc((size_t)NCONP_ * D_ * 4));
  u16*   W1T  = (u16*)  (w + alloc((size_t)HID_ * TDIM_ * 2));
  u16*   W2T  = (u16*)  (w + alloc((size_t)D_ * HID_ * 2));
  u16*   WxhT = (u16*)  (w + alloc((size_t)256 * 320 * 2));
  float* bxh  = (float*)(w + alloc((size_t)256 * 4));

  k_prep<<<6017, 256, 0, stream>>>(ex, prob_ids, con, W1, W2, Wx, Wh, bx, bh,
                                   qb, qn, cb, cb8, cn, W1T, W2T, WxhT, bxh);
  k_mlp<<<576, 512, 0, stream>>>(qb, cb, W1T, b1, W2T, b2, redq, redc);
  k_mixgru<<<512, 512, 0, stream>>>(qb, cb8, qn, cn, rci, filt, redq, redc,
                                    h, emb, op, Wp, bp, WxhT, bxh, out, out + B_);
}